// Round 1
// baseline (11032.044 us; speedup 1.0000x reference)
//
#include <hip/hip_runtime.h>
#include <hip/hip_bf16.h>

#define B_ 32
#define S_ 512
#define V_ 8000
#define I_ 256
#define H_ 512
#define LN_EPS 1e-5f

// ---------------- transpose: out[c][r] = in[r][c], R,C multiples of 32 ----------------
__global__ void k_transpose(const float* __restrict__ in, float* __restrict__ out,
                            int R, int C) {
    __shared__ float tile[32][33];
    int c0 = blockIdx.x * 32, r0 = blockIdx.y * 32;
    int tx = threadIdx.x, ty = threadIdx.y;  // block (32,8)
#pragma unroll
    for (int i = 0; i < 32; i += 8)
        tile[ty + i][tx] = in[(size_t)(r0 + ty + i) * C + (c0 + tx)];
    __syncthreads();
#pragma unroll
    for (int i = 0; i < 32; i += 8)
        out[(size_t)(c0 + ty + i) * R + (r0 + tx)] = tile[tx][ty + i];
}

// ---------------- embed gather + input projection ----------------
// Xp[(s*B+b)*H + j] = b_in[j] + sum_i emb[x_idx[b,s]*I + i] * WinT[i*H + j]
// block: 512 threads, handles 8 consecutive m-rows (m = s*B+b)
__global__ __launch_bounds__(512) void k_embed_proj(
        const int* __restrict__ x_idx, const float* __restrict__ emb,
        const float* __restrict__ WinT, const float* __restrict__ b_in,
        float* __restrict__ Xp) {
    __shared__ float e[8][I_];
    const int m0 = blockIdx.x * 8;
    const int t = threadIdx.x;

    // cooperative load of 8 embedding rows (1 wave per row, float4 coalesced)
    {
        int r = t >> 6, i4 = (t & 63) * 4;
        int m = m0 + r;
        int s = m >> 5, b = m & 31;           // m = s*B + b, B=32
        int idx = x_idx[b * S_ + s];
        *(float4*)&e[r][i4] = *(const float4*)&emb[(size_t)idx * I_ + i4];
    }
    __syncthreads();

    const int j = t;
    float acc[8];
    const float bj = b_in[j];
#pragma unroll
    for (int r = 0; r < 8; ++r) acc[r] = bj;

    for (int i = 0; i < I_; ++i) {
        float w = WinT[(size_t)i * H_ + j];   // coalesced across threads
#pragma unroll
        for (int r = 0; r < 8; ++r) acc[r] += e[r][i] * w;
    }
#pragma unroll
    for (int r = 0; r < 8; ++r)
        Xp[(size_t)(m0 + r) * H_ + j] = acc[r];
}

// ---------------- recurrent scan: 1 workgroup per batch row, no grid syncs ----------------
__global__ __launch_bounds__(512) void k_scan(
        const float* __restrict__ Xp,
        const float* __restrict__ WrecT, const float* __restrict__ b_rec,
        const float* __restrict__ WtrT,  const float* __restrict__ b_tr,
        const float* __restrict__ gamma, const float* __restrict__ beta,
        float* __restrict__ hs) {
    __shared__ float h_s[H_];
    __shared__ float t_s[H_];
    __shared__ float red[16];
    __shared__ float mv[2];

    const int b = blockIdx.x;
    const int j = threadIdx.x;
    const float brj = b_rec[j], btj = b_tr[j], gj = gamma[j], bej = beta[j];

    h_s[j] = 0.f;
    __syncthreads();

    for (int s = 0; s < S_; ++s) {
        const size_t m = (size_t)s * B_ + b;

        // h_t = tanh(Xp + h @ W_rec^T + b_rec)
        float acc = Xp[m * H_ + j] + brj;
#pragma unroll 4
        for (int k = 0; k < H_; k += 4) {
            float4 h4 = *(const float4*)&h_s[k];      // LDS broadcast
            acc += h4.x * WrecT[(size_t)(k + 0) * H_ + j];
            acc += h4.y * WrecT[(size_t)(k + 1) * H_ + j];
            acc += h4.z * WrecT[(size_t)(k + 2) * H_ + j];
            acc += h4.w * WrecT[(size_t)(k + 3) * H_ + j];
        }
        float ht = tanhf(acc);
        t_s[j] = ht;                                   // different buffer than h_s: no hazard
        __syncthreads();                               // t_s ready (also fences h_s reads)

        // u = tanh(h_t @ W_tr^T + b_tr)
        float acc2 = btj;
#pragma unroll 4
        for (int k = 0; k < H_; k += 4) {
            float4 h4 = *(const float4*)&t_s[k];
            acc2 += h4.x * WtrT[(size_t)(k + 0) * H_ + j];
            acc2 += h4.y * WtrT[(size_t)(k + 1) * H_ + j];
            acc2 += h4.z * WtrT[(size_t)(k + 2) * H_ + j];
            acc2 += h4.w * WtrT[(size_t)(k + 3) * H_ + j];
        }
        float u = tanhf(acc2);

        // LayerNorm over the 512 lanes of this block
        float s1 = u, s2 = u * u;
#pragma unroll
        for (int off = 32; off >= 1; off >>= 1) {      // wave64 butterfly
            s1 += __shfl_down(s1, off);
            s2 += __shfl_down(s2, off);
        }
        int lane = j & 63, wid = j >> 6;
        if (lane == 0) { red[wid] = s1; red[8 + wid] = s2; }
        __syncthreads();
        if (j == 0) {
            float a1 = 0.f, a2 = 0.f;
#pragma unroll
            for (int w = 0; w < 8; ++w) { a1 += red[w]; a2 += red[8 + w]; }
            float mean = a1 * (1.0f / H_);
            float var  = a2 * (1.0f / H_) - mean * mean;
            mv[0] = mean;
            mv[1] = rsqrtf(var + LN_EPS);
        }
        __syncthreads();

        float hn = (u - mv[0]) * mv[1] * gj + bej;
        h_s[j] = hn;                                   // all h_s/t_s reads fenced above
        hs[m * H_ + j] = hn;
        __syncthreads();                               // h_s ready for next step
    }
}

// ---------------- output GEMM: y[b,s,v] = hs[s,b,:] . W_out[v,:] + b_out[v] ----------------
// M=16384 (m = s*B+b), N=8000, K=512. 64x64 tile, 256 threads, 4x4 per thread.
__global__ __launch_bounds__(256) void k_out_gemm(
        const float* __restrict__ hs, const float* __restrict__ W_out,
        const float* __restrict__ b_out, float* __restrict__ y) {
    __shared__ float Ast[16][68];   // [k][m], padded
    __shared__ float Bs[16][68];    // [k][v], padded

    const int v0 = blockIdx.x * 64;
    const int m0 = blockIdx.y * 64;
    const int t  = threadIdx.x;
    const int tx = t & 15, ty = t >> 4;

    float acc[4][4] = {};

    for (int k0 = 0; k0 < H_; k0 += 16) {
        const int kk = t & 15;
        const int mm = (t >> 4) << 2;
#pragma unroll
        for (int q = 0; q < 4; ++q)
            Ast[kk][mm + q] = hs[(size_t)(m0 + mm + q) * H_ + k0 + kk];
#pragma unroll
        for (int q = 0; q < 4; ++q)
            Bs[kk][mm + q] = W_out[(size_t)(v0 + mm + q) * H_ + k0 + kk];
        __syncthreads();

#pragma unroll
        for (int k = 0; k < 16; ++k) {
            float4 a4 = *(const float4*)&Ast[k][ty * 4];
            float4 b4 = *(const float4*)&Bs[k][tx * 4];
            float a[4] = {a4.x, a4.y, a4.z, a4.w};
            float bb[4] = {b4.x, b4.y, b4.z, b4.w};
#pragma unroll
            for (int i = 0; i < 4; ++i)
#pragma unroll
                for (int jq = 0; jq < 4; ++jq)
                    acc[i][jq] += a[i] * bb[jq];
        }
        __syncthreads();
    }

#pragma unroll
    for (int i = 0; i < 4; ++i) {
        int m = m0 + ty * 4 + i;
        int s = m >> 5, b = m & 31;                 // m = s*B + b
        size_t row = ((size_t)b * S_ + s) * V_;
        int v = v0 + tx * 4;
        float4 r;
        r.x = acc[i][0] + b_out[v + 0];
        r.y = acc[i][1] + b_out[v + 1];
        r.z = acc[i][2] + b_out[v + 2];
        r.w = acc[i][3] + b_out[v + 3];
        *(float4*)&y[row + v] = r;
    }
}

extern "C" void kernel_launch(void* const* d_in, const int* in_sizes, int n_in,
                              void* d_out, int out_size, void* d_ws, size_t ws_size,
                              hipStream_t stream) {
    const int*   x_idx = (const int*)d_in[0];
    const float* emb   = (const float*)d_in[1];
    const float* W_in  = (const float*)d_in[2];
    const float* b_in  = (const float*)d_in[3];
    const float* W_rec = (const float*)d_in[4];
    const float* b_rec = (const float*)d_in[5];
    const float* W_tr  = (const float*)d_in[6];
    const float* b_tr  = (const float*)d_in[7];
    const float* gamma = (const float*)d_in[8];
    const float* beta  = (const float*)d_in[9];
    const float* W_out = (const float*)d_in[10];
    const float* b_out = (const float*)d_in[11];
    float* y  = (float*)d_out;
    float* ws = (float*)d_ws;

    // workspace layout (floats): total ~17.4M floats = 66.5 MB
    float* WinT  = ws;                 // 256*512   = 131072
    float* WrecT = ws + 131072;        // 512*512   = 262144
    float* WtrT  = ws + 393216;        // 512*512   = 262144
    float* Xp    = ws + 655360;        // 16384*512 = 8388608
    float* hs    = ws + 9043968;       // 16384*512 = 8388608

    dim3 tb(32, 8);
    k_transpose<<<dim3(I_ / 32, H_ / 32), tb, 0, stream>>>(W_in,  WinT,  H_, I_);
    k_transpose<<<dim3(H_ / 32, H_ / 32), tb, 0, stream>>>(W_rec, WrecT, H_, H_);
    k_transpose<<<dim3(H_ / 32, H_ / 32), tb, 0, stream>>>(W_tr,  WtrT,  H_, H_);

    k_embed_proj<<<(B_ * S_) / 8, 512, 0, stream>>>(x_idx, emb, WinT, b_in, Xp);

    k_scan<<<B_, 512, 0, stream>>>(Xp, WrecT, b_rec, WtrT, b_tr, gamma, beta, hs);

    k_out_gemm<<<dim3(V_ / 64, (B_ * S_) / 64), 256, 0, stream>>>(hs, W_out, b_out, y);
}